// Round 1
// baseline (615.032 us; speedup 1.0000x reference)
//
#include <hip/hip_runtime.h>
#include <math.h>

#define DI __device__ __forceinline__

namespace {

constexpr int PB = 32768;   // batch

DI int permq(int x) { return ((x >> 2) | ((x & 3) << 5)) & 127; }

// ---------------- precompute kernels (all tiny) ----------------

// M[i][c][k] = sum_j Wo[i][c][j] * Wv[i][j][k];  beff[i][c] = Wo[i][c]·bv[i] + bo[i][c]
__global__ void k_weff(const float* __restrict__ Wqkv, const float* __restrict__ bqkv,
                       const float* __restrict__ Wo, const float* __restrict__ bo,
                       float* __restrict__ M, float* __restrict__ beff)
{
  const int i = blockIdx.x >> 7;
  const int c = blockIdx.x & 127;
  const int k = threadIdx.x;
  const float* wo_row = Wo + (size_t)(i*128 + c)*128;
  const float* wv = Wqkv + (size_t)(i*384 + 256)*128;
  float acc = 0.f;
#pragma unroll 4
  for (int j = 0; j < 128; ++j)
    acc = fmaf(wo_row[j], wv[j*128 + k], acc);
  M[(size_t)(i*128 + c)*128 + k] = acc;

  __shared__ float red[128];
  const float* bv = bqkv + i*384 + 256;
  red[k] = wo_row[k] * bv[k];
  __syncthreads();
  for (int s = 64; s > 0; s >>= 1) {
    if (k < s) red[k] += red[k + s];
    __syncthreads();
  }
  if (k == 0) beff[i*128 + c] = red[0] + bo[i*128 + c];
}

// Nbig[c][i*128+k] = sum_j Wf1[c][i*128+j] * M[i][j][k];  cvec[i][c] = Wf1[c][i-slice]·beff[i]
__global__ void k_nbig(const float* __restrict__ Wf1, const float* __restrict__ M,
                       const float* __restrict__ beff,
                       float* __restrict__ Nbig, float* __restrict__ cvec)
{
  const int i = blockIdx.x >> 8;
  const int c = blockIdx.x & 255;
  const int k = threadIdx.x;
  const float* w_row = Wf1 + (size_t)c*768 + i*128;
  const float* Mi = M + (size_t)i*128*128;
  float acc = 0.f;
#pragma unroll 4
  for (int j = 0; j < 128; ++j)
    acc = fmaf(w_row[j], Mi[j*128 + k], acc);
  Nbig[(size_t)c*768 + i*128 + k] = acc;

  __shared__ float red[128];
  red[k] = w_row[k] * beff[i*128 + k];
  __syncthreads();
  for (int s = 64; s > 0; s >>= 1) {
    if (k < s) red[k] += red[k + s];
    __syncthreads();
  }
  if (k == 0) cvec[i*256 + c] = red[0];
}

// Ghat[j][src*128+k] = sum_{i in pair(src)} sum_c M[i][c][k] * Wg[j][i*128+c]
__global__ void k_ghat(const float* __restrict__ M, const float* __restrict__ Wg,
                       float* __restrict__ Ghat)
{
  const int j = blockIdx.x / 3;
  const int src = blockIdx.x % 3;
  const int k = threadIdx.x;
  int i0, i1;
  if (src == 0)      { i0 = 2; i1 = 4; }   // t fed to branches 2,4
  else if (src == 1) { i0 = 0; i1 = 5; }   // v fed to branches 0,5
  else               { i0 = 1; i1 = 3; }   // a fed to branches 1,3
  float acc = 0.f;
  for (int t = 0; t < 2; ++t) {
    const int i = t ? i1 : i0;
    const float* Mi = M + (size_t)i*128*128;
    const float* wg = Wg + j*768 + i*128;
#pragma unroll 4
    for (int c = 0; c < 128; ++c)
      acc = fmaf(Mi[c*128 + k], wg[c], acc);
  }
  Ghat[j*384 + src*128 + k] = acc;
}

// svec[j] = sum_i beff[i]·Wg[j][i-slice] + bg[j]
__global__ void k_svec(const float* __restrict__ beff, const float* __restrict__ Wg,
                       const float* __restrict__ bg, float* __restrict__ svec)
{
  const int j = blockIdx.x;
  const int c = threadIdx.x;
  float p = 0.f;
#pragma unroll
  for (int i = 0; i < 6; ++i)
    p = fmaf(beff[i*128 + c], Wg[j*768 + i*128 + c], p);
  __shared__ float red[128];
  red[c] = p;
  __syncthreads();
  for (int s = 64; s > 0; s >>= 1) {
    if (c < s) red[c] += red[c + s];
    __syncthreads();
  }
  if (c == 0) svec[j] = red[0] + bg[j];
}

// ---------------- main tiled GEMM (fp32, 128x128 tile, 8x8 microtile) ----------------
// MODE 0: proj  out[r][colOff+c] = ReLU(LN(x@W^T + bias))        (out stride 384)
// MODE 1: f1    A = g-scaled tva; epilogue += bf1 + sum_i g_i*cvec_i; ReLU
// MODE 2: f2    epilogue += bias; ReLU
template<int KDIM, int MODE>
__global__ __launch_bounds__(256, 2)
void k_gemm(const float* __restrict__ X, const float* __restrict__ W,
            const float* __restrict__ bias, const float* __restrict__ p0,
            const float* __restrict__ p1, float* __restrict__ out,
            int outStride, int colOff0)
{
  __shared__ float4 As[1024];
  __shared__ float4 Bs[1024];
  __shared__ float gS[(MODE == 1) ? 768 : 4];

  const int tid = threadIdx.x;
  const int row0 = blockIdx.x * 128;
  const int colOff = colOff0 + blockIdx.y * 128;
  const int cg = tid & 15, rg = tid >> 4;

  if constexpr (MODE == 1) {
    for (int idx = tid; idx < 768; idx += 256) gS[idx] = p0[(size_t)row0*6 + idx];
  }

  int pa[8], pb[8];
#pragma unroll
  for (int i = 0; i < 4; ++i) {
    pa[i]     = permq(rg*4 + i);
    pa[i + 4] = permq(64 + rg*4 + i);
    pb[i]     = permq(cg*4 + i);
    pb[i + 4] = permq(64 + cg*4 + i);
  }

  float acc[8][8];
#pragma unroll
  for (int i = 0; i < 8; ++i)
#pragma unroll
    for (int j = 0; j < 8; ++j) acc[i][j] = 0.f;

  const int lr  = tid >> 3;   // 0..31
  const int lk4 = tid & 7;    // 0..7

  for (int kc = 0; kc < KDIM; kc += 32) {
    __syncthreads();
#pragma unroll
    for (int it = 0; it < 4; ++it) {
      const int r = it*32 + lr;
      float4 av;
      if constexpr (MODE == 1) {
        const int k = kc + lk4*4;
        const int br = k >> 7;
        const int src = (0x102021 >> (br*4)) & 3;
        av = *reinterpret_cast<const float4*>(X + (size_t)(row0 + r)*384 + src*128 + (k & 127));
        const float s = gS[r*6 + br];
        av.x *= s; av.y *= s; av.z *= s; av.w *= s;
      } else {
        av = *reinterpret_cast<const float4*>(X + (size_t)(row0 + r)*KDIM + kc + lk4*4);
      }
      const int wrow = (MODE != 0 ? colOff : 0) + r;
      const float4 bv = *reinterpret_cast<const float4*>(W + (size_t)wrow*KDIM + kc + lk4*4);
      const int sidx = lk4*128 + (permq(r) ^ lk4);
      As[sidx] = av;
      Bs[sidx] = bv;
    }
    __syncthreads();
#pragma unroll
    for (int k4 = 0; k4 < 8; ++k4) {
      float4 af[8], bf[8];
#pragma unroll
      for (int i = 0; i < 8; ++i) af[i] = As[k4*128 + (pa[i] ^ k4)];
#pragma unroll
      for (int j = 0; j < 8; ++j) bf[j] = Bs[k4*128 + (pb[j] ^ k4)];
#pragma unroll
      for (int i = 0; i < 8; ++i)
#pragma unroll
        for (int j = 0; j < 8; ++j) {
          acc[i][j] = fmaf(af[i].x, bf[j].x, acc[i][j]);
          acc[i][j] = fmaf(af[i].y, bf[j].y, acc[i][j]);
          acc[i][j] = fmaf(af[i].z, bf[j].z, acc[i][j]);
          acc[i][j] = fmaf(af[i].w, bf[j].w, acc[i][j]);
        }
    }
  }

  int ccol[8], rrow[8];
#pragma unroll
  for (int j = 0; j < 4; ++j) { ccol[j] = cg*4 + j; ccol[j+4] = 64 + cg*4 + j; }
#pragma unroll
  for (int i = 0; i < 4; ++i) { rrow[i] = rg*4 + i; rrow[i+4] = 64 + rg*4 + i; }

  if constexpr (MODE == 0) {
    float bcol[8], lwv[8], lbv[8];
#pragma unroll
    for (int j = 0; j < 8; ++j) {
      bcol[j] = bias[ccol[j]];
      lwv[j] = p0[ccol[j]];
      lbv[j] = p1[ccol[j]];
    }
#pragma unroll
    for (int i = 0; i < 8; ++i) {
      float s = 0.f, q = 0.f;
#pragma unroll
      for (int j = 0; j < 8; ++j) {
        const float h = acc[i][j] + bcol[j];
        acc[i][j] = h;
        s += h;
        q = fmaf(h, h, q);
      }
#pragma unroll
      for (int m = 1; m <= 8; m <<= 1) {
        s += __shfl_xor(s, m);
        q += __shfl_xor(q, m);
      }
      const float mean = s * (1.f/128.f);
      const float var  = q * (1.f/128.f) - mean*mean;
      const float rstd = rsqrtf(var + 1e-5f);
      float o[8];
#pragma unroll
      for (int j = 0; j < 8; ++j) {
        const float v = fmaf((acc[i][j] - mean)*rstd, lwv[j], lbv[j]);
        o[j] = fmaxf(v, 0.f);
      }
      float* orow = out + (size_t)(row0 + rrow[i])*outStride + colOff;
      *reinterpret_cast<float4*>(orow + cg*4)      = make_float4(o[0], o[1], o[2], o[3]);
      *reinterpret_cast<float4*>(orow + 64 + cg*4) = make_float4(o[4], o[5], o[6], o[7]);
    }
  } else if constexpr (MODE == 1) {
    float bcol[8];
    float cv[6][8];
#pragma unroll
    for (int j = 0; j < 8; ++j) {
      const int gc = colOff + ccol[j];
      bcol[j] = bias[gc];
#pragma unroll
      for (int br = 0; br < 6; ++br) cv[br][j] = p1[br*256 + gc];
    }
#pragma unroll
    for (int i = 0; i < 8; ++i) {
      const int rl = rrow[i];
      const float g0 = gS[rl*6+0], g1 = gS[rl*6+1], g2 = gS[rl*6+2];
      const float g3 = gS[rl*6+3], g4 = gS[rl*6+4], g5 = gS[rl*6+5];
      float o[8];
#pragma unroll
      for (int j = 0; j < 8; ++j) {
        float v = acc[i][j] + bcol[j];
        v = fmaf(g0, cv[0][j], v); v = fmaf(g1, cv[1][j], v);
        v = fmaf(g2, cv[2][j], v); v = fmaf(g3, cv[3][j], v);
        v = fmaf(g4, cv[4][j], v); v = fmaf(g5, cv[5][j], v);
        o[j] = fmaxf(v, 0.f);
      }
      float* orow = out + (size_t)(row0 + rl)*outStride + colOff;
      *reinterpret_cast<float4*>(orow + cg*4)      = make_float4(o[0], o[1], o[2], o[3]);
      *reinterpret_cast<float4*>(orow + 64 + cg*4) = make_float4(o[4], o[5], o[6], o[7]);
    }
  } else {
    float bcol[8];
#pragma unroll
    for (int j = 0; j < 8; ++j) bcol[j] = bias[colOff + ccol[j]];
#pragma unroll
    for (int i = 0; i < 8; ++i) {
      float o[8];
#pragma unroll
      for (int j = 0; j < 8; ++j) o[j] = fmaxf(acc[i][j] + bcol[j], 0.f);
      float* orow = out + (size_t)(row0 + rrow[i])*outStride + colOff;
      *reinterpret_cast<float4*>(orow + cg*4)      = make_float4(o[0], o[1], o[2], o[3]);
      *reinterpret_cast<float4*>(orow + 64 + cg*4) = make_float4(o[4], o[5], o[6], o[7]);
    }
  }
}

// gate: z = tva_row·Ghat^T + svec -> softmax(6) -> g[row][6]   (one wave per row)
__global__ __launch_bounds__(256)
void k_gate(const float* __restrict__ tva, const float* __restrict__ Ghat,
            const float* __restrict__ svec, float* __restrict__ g)
{
  __shared__ float Gs[6*384];
  __shared__ float ss[6];
  const int tid = threadIdx.x;
  for (int idx = tid; idx < 2304; idx += 256) Gs[idx] = Ghat[idx];
  if (tid < 6) ss[tid] = svec[tid];
  __syncthreads();

  const int lane = tid & 63;
  const int row = blockIdx.x*4 + (tid >> 6);
  const float* xr = tva + (size_t)row*384;
  float a0=0,a1=0,a2=0,a3=0,a4=0,a5=0;
#pragma unroll
  for (int m = 0; m < 6; ++m) {
    const int k = m*64 + lane;
    const float x = xr[k];
    a0 = fmaf(x, Gs[0*384+k], a0);
    a1 = fmaf(x, Gs[1*384+k], a1);
    a2 = fmaf(x, Gs[2*384+k], a2);
    a3 = fmaf(x, Gs[3*384+k], a3);
    a4 = fmaf(x, Gs[4*384+k], a4);
    a5 = fmaf(x, Gs[5*384+k], a5);
  }
#pragma unroll
  for (int m = 1; m < 64; m <<= 1) {
    a0 += __shfl_xor(a0, m); a1 += __shfl_xor(a1, m); a2 += __shfl_xor(a2, m);
    a3 += __shfl_xor(a3, m); a4 += __shfl_xor(a4, m); a5 += __shfl_xor(a5, m);
  }
  a0 += ss[0]; a1 += ss[1]; a2 += ss[2]; a3 += ss[3]; a4 += ss[4]; a5 += ss[5];
  const float mx = fmaxf(fmaxf(fmaxf(a0,a1),fmaxf(a2,a3)),fmaxf(a4,a5));
  const float e0 = expf(a0-mx), e1 = expf(a1-mx), e2 = expf(a2-mx);
  const float e3 = expf(a3-mx), e4 = expf(a4-mx), e5 = expf(a5-mx);
  const float inv = 1.f / (e0+e1+e2+e3+e4+e5);
  if (lane == 0) {
    float* gr = g + (size_t)row*6;
    gr[0]=e0*inv; gr[1]=e1*inv; gr[2]=e2*inv; gr[3]=e3*inv; gr[4]=e4*inv; gr[5]=e5*inv;
  }
}

// final: out = h2 @ Wout^T + bout    (one wave per row)
__global__ __launch_bounds__(256)
void k_out(const float* __restrict__ h2, const float* __restrict__ Wout,
           const float* __restrict__ bout, float* __restrict__ out)
{
  __shared__ __align__(16) float Ws[512];
  const int tid = threadIdx.x;
  for (int idx = tid; idx < 512; idx += 256) Ws[idx] = Wout[idx];
  __syncthreads();
  const int lane = tid & 63;
  const int row = blockIdx.x*4 + (tid >> 6);
  const float4 x  = *reinterpret_cast<const float4*>(h2 + (size_t)row*256 + lane*4);
  const float4 w0 = *reinterpret_cast<const float4*>(Ws + lane*4);
  const float4 w1 = *reinterpret_cast<const float4*>(Ws + 256 + lane*4);
  float s0 = x.x*w0.x + x.y*w0.y + x.z*w0.z + x.w*w0.w;
  float s1 = x.x*w1.x + x.y*w1.y + x.z*w1.z + x.w*w1.w;
#pragma unroll
  for (int m = 1; m < 64; m <<= 1) { s0 += __shfl_xor(s0, m); s1 += __shfl_xor(s1, m); }
  if (lane == 0) {
    out[(size_t)row*2]     = s0 + bout[0];
    out[(size_t)row*2 + 1] = s1 + bout[1];
  }
}

} // namespace

extern "C" void kernel_launch(void* const* d_in, const int* in_sizes, int n_in,
                              void* d_out, int out_size, void* d_ws, size_t ws_size,
                              hipStream_t stream)
{
  const float* xt   = (const float*)d_in[0];
  const float* xv   = (const float*)d_in[1];
  const float* xa   = (const float*)d_in[2];
  const float* Wt   = (const float*)d_in[3];
  const float* bt   = (const float*)d_in[4];
  const float* lnwt = (const float*)d_in[5];
  const float* lnbt = (const float*)d_in[6];
  const float* Wv   = (const float*)d_in[7];
  const float* bv   = (const float*)d_in[8];
  const float* lnwv = (const float*)d_in[9];
  const float* lnbv = (const float*)d_in[10];
  const float* Wa   = (const float*)d_in[11];
  const float* ba   = (const float*)d_in[12];
  const float* lnwa = (const float*)d_in[13];
  const float* lnba = (const float*)d_in[14];
  const float* Wqkv = (const float*)d_in[15];
  const float* bqkv = (const float*)d_in[16];
  const float* Wo   = (const float*)d_in[17];
  const float* bo   = (const float*)d_in[18];
  const float* Wg   = (const float*)d_in[19];
  const float* bg   = (const float*)d_in[20];
  const float* Wf1  = (const float*)d_in[21];
  const float* bf1  = (const float*)d_in[22];
  const float* Wf2  = (const float*)d_in[23];
  const float* bf2  = (const float*)d_in[24];
  const float* Woutp= (const float*)d_in[25];
  const float* boutp= (const float*)d_in[26];
  float* out = (float*)d_out;

  float* ws   = (float*)d_ws;
  float* tva  = ws;                          // 32768*384
  float* g    = tva  + (size_t)PB*384;       // 32768*6
  float* h1   = g    + (size_t)PB*6;         // 32768*256
  float* M    = h1   + (size_t)PB*256;       // 6*128*128
  float* beff = M    + 6*128*128;            // 768
  float* Nbig = beff + 768;                  // 256*768
  float* cvec = Nbig + 256*768;              // 6*256
  float* Ghat = cvec + 6*256;                // 6*384
  float* svec = Ghat + 6*384;                // 6
  float* h2   = tva;                         // alias: tva dead after f1

  // weight composition (order matters: M/beff first)
  k_weff<<<768, 128, 0, stream>>>(Wqkv, bqkv, Wo, bo, M, beff);
  k_nbig<<<1536, 128, 0, stream>>>(Wf1, M, beff, Nbig, cvec);
  k_ghat<<<18, 128, 0, stream>>>(M, Wg, Ghat);
  k_svec<<<6, 128, 0, stream>>>(beff, Wg, bg, svec);

  // projections -> tva [B][384] (t|v|a)
  k_gemm<768, 0><<<dim3(256, 1), 256, 0, stream>>>(xt, Wt, bt, lnwt, lnbt, tva, 384, 0);
  k_gemm<512, 0><<<dim3(256, 1), 256, 0, stream>>>(xv, Wv, bv, lnwv, lnbv, tva, 384, 128);
  k_gemm<384, 0><<<dim3(256, 1), 256, 0, stream>>>(xa, Wa, ba, lnwa, lnba, tva, 384, 256);

  // gate
  k_gate<<<PB/4, 256, 0, stream>>>(tva, Ghat, svec, g);

  // f1 (gated, fused branch+f1 weights), f2, head
  k_gemm<768, 1><<<dim3(256, 2), 256, 0, stream>>>(tva, Nbig, bf1, g, cvec, h1, 256, 0);
  k_gemm<256, 2><<<dim3(256, 2), 256, 0, stream>>>(h1, Wf2, bf2, nullptr, nullptr, h2, 256, 0);
  k_out<<<PB/4, 256, 0, stream>>>(h2, Woutp, boutp, out);
}

// Round 2
// 251.813 us; speedup vs baseline: 2.4424x; 2.4424x over previous
//
#include <hip/hip_runtime.h>
#include <math.h>

#define DI __device__ __forceinline__

namespace {

constexpr int PB = 32768;   // batch

typedef _Float16 half_t;
typedef float f32x4 __attribute__((ext_vector_type(4)));
typedef _Float16 f16x8 __attribute__((ext_vector_type(8)));
typedef unsigned int u32x4 __attribute__((ext_vector_type(4)));

#define MFMA16 __builtin_amdgcn_mfma_f32_16x16x32_f16

DI void gl16(const void* g, void* l) {
  __builtin_amdgcn_global_load_lds((const __attribute__((address_space(1))) void*)g,
                                   (__attribute__((address_space(3))) void*)l, 16, 0, 0);
}
DI f16x8 asH(f32x4 v) { return __builtin_bit_cast(f16x8, v); }

// ---------------- precompute kernels (all tiny) ----------------

// M[i][c][k] = sum_j Wo[i][c][j] * Wv[i][j][k];  beff[i][c] = Wo[i][c]·bv[i] + bo[i][c]
__global__ void k_weff(const float* __restrict__ Wqkv, const float* __restrict__ bqkv,
                       const float* __restrict__ Wo, const float* __restrict__ bo,
                       float* __restrict__ M, float* __restrict__ beff)
{
  const int i = blockIdx.x >> 7;
  const int c = blockIdx.x & 127;
  const int k = threadIdx.x;
  const float* wo_row = Wo + (size_t)(i*128 + c)*128;
  const float* wv = Wqkv + (size_t)(i*384 + 256)*128;
  float acc = 0.f;
#pragma unroll 4
  for (int j = 0; j < 128; ++j)
    acc = fmaf(wo_row[j], wv[j*128 + k], acc);
  M[(size_t)(i*128 + c)*128 + k] = acc;

  __shared__ float red[128];
  const float* bv = bqkv + i*384 + 256;
  red[k] = wo_row[k] * bv[k];
  __syncthreads();
  for (int s = 64; s > 0; s >>= 1) {
    if (k < s) red[k] += red[k + s];
    __syncthreads();
  }
  if (k == 0) beff[i*128 + c] = red[0] + bo[i*128 + c];
}

// N planes: Nh/Nl[c][k] (k<800), value 4096*(Wf1·M) ; k=768+i column = 4096*cvec_i ; pad zero
__global__ void k_nbig2(const float* __restrict__ Wf1, const float* __restrict__ M,
                        const float* __restrict__ beff,
                        half_t* __restrict__ Nh, half_t* __restrict__ Nl)
{
  const int i = blockIdx.x >> 8;
  const int c = blockIdx.x & 255;
  const int k = threadIdx.x;
  const float* w_row = Wf1 + (size_t)c*768 + i*128;
  const float* Mi = M + (size_t)i*128*128;
  float acc = 0.f;
#pragma unroll 4
  for (int j = 0; j < 128; ++j)
    acc = fmaf(w_row[j], Mi[j*128 + k], acc);
  float v = acc * 4096.f;
  half_t hi = (half_t)v;
  Nh[(size_t)c*800 + i*128 + k] = hi;
  Nl[(size_t)c*800 + i*128 + k] = (half_t)(v - (float)hi);

  __shared__ float red[128];
  red[k] = w_row[k] * beff[i*128 + k];
  __syncthreads();
  for (int s = 64; s > 0; s >>= 1) {
    if (k < s) red[k] += red[k + s];
    __syncthreads();
  }
  if (k == 0) {
    float cv = red[0] * 4096.f;
    half_t ch = (half_t)cv;
    Nh[(size_t)c*800 + 768 + i] = ch;
    Nl[(size_t)c*800 + 768 + i] = (half_t)(cv - (float)ch);
  }
  if (i == 0 && k < 26) {
    Nh[(size_t)c*800 + 774 + k] = (half_t)0.f;
    Nl[(size_t)c*800 + 774 + k] = (half_t)0.f;
  }
}

// Ghat[j][src*128+k] = sum_{i in pair(src)} sum_c M[i][c][k] * Wg[j][i*128+c]
__global__ void k_ghat(const float* __restrict__ M, const float* __restrict__ Wg,
                       float* __restrict__ Ghat)
{
  const int j = blockIdx.x / 3;
  const int src = blockIdx.x % 3;
  const int k = threadIdx.x;
  int i0, i1;
  if (src == 0)      { i0 = 2; i1 = 4; }
  else if (src == 1) { i0 = 0; i1 = 5; }
  else               { i0 = 1; i1 = 3; }
  float acc = 0.f;
  for (int t = 0; t < 2; ++t) {
    const int i = t ? i1 : i0;
    const float* Mi = M + (size_t)i*128*128;
    const float* wg = Wg + j*768 + i*128;
#pragma unroll 4
    for (int c = 0; c < 128; ++c)
      acc = fmaf(Mi[c*128 + k], wg[c], acc);
  }
  Ghat[j*384 + src*128 + k] = acc;
}

// svec[j] = sum_i beff[i]·Wg[j][i-slice] + bg[j]
__global__ void k_svec(const float* __restrict__ beff, const float* __restrict__ Wg,
                       const float* __restrict__ bg, float* __restrict__ svec)
{
  const int j = blockIdx.x;
  const int c = threadIdx.x;
  float p = 0.f;
#pragma unroll
  for (int i = 0; i < 6; ++i)
    p = fmaf(beff[i*128 + c], Wg[j*768 + i*128 + c], p);
  __shared__ float red[128];
  red[c] = p;
  __syncthreads();
  for (int s = 64; s > 0; s >>= 1) {
    if (c < s) red[c] += red[c + s];
    __syncthreads();
  }
  if (c == 0) svec[j] = red[0] + bg[j];
}

// split fp32 -> scaled fp16 hi/lo planes
__global__ void k_split(const float* __restrict__ in, half_t* __restrict__ hi,
                        half_t* __restrict__ lo, float scale, int n)
{
  const int i = blockIdx.x*256 + threadIdx.x;
  if (i < n) {
    float v = in[i] * scale;
    half_t h = (half_t)v;
    hi[i] = h;
    lo[i] = (half_t)(v - (float)h);
  }
}

// ---------------- proj GEMM: 64x128 tile, MFMA split-fp16, LN+ReLU+z-partial ----------------
template<int KD>
__global__ __launch_bounds__(256, 2)
void k_proj(const float* __restrict__ X, const half_t* __restrict__ Bh_,
            const half_t* __restrict__ Bl_, const float* __restrict__ bias,
            const float* __restrict__ lnw, const float* __restrict__ lnb,
            const float* __restrict__ Ghat, float* __restrict__ tva,
            float* __restrict__ zpart, int colOff, int srcIdx)
{
  __shared__ f32x4 As[512];    // (pl*4+kb)*64 + r
  __shared__ f32x4 Bs[1024];   // (pl*4+kb)*128 + r
  const int tid = threadIdx.x;
  const int row0 = blockIdx.x * 64;
  const int lane = tid & 63, wid = tid >> 6;
  const int l15 = lane & 15, l4 = lane >> 4;
  const int sr = tid >> 2, skq = tid & 3;

  f32x4 acc[8];
#pragma unroll
  for (int i = 0; i < 8; ++i) acc[i] = f32x4{0.f, 0.f, 0.f, 0.f};

  for (int kc = 0; kc < KD; kc += 32) {
    { // A stage: 8 elems/thread, split to hi/lo
      const f32x4* xp = reinterpret_cast<const f32x4*>(X + (size_t)(row0 + sr)*KD + kc + skq*8);
      f32x4 v0 = xp[0], v1 = xp[1];
      float e[8] = {v0[0], v0[1], v0[2], v0[3], v1[0], v1[1], v1[2], v1[3]};
      f16x8 hv, lv;
#pragma unroll
      for (int j = 0; j < 8; ++j) {
        half_t h = (half_t)e[j];
        float lo = e[j] - (float)h;
        hv[j] = h; lv[j] = (half_t)lo;
      }
      As[skq*64 + sr]       = __builtin_bit_cast(f32x4, hv);
      As[(4 + skq)*64 + sr] = __builtin_bit_cast(f32x4, lv);
    }
    // B stage: pre-split planes via global_load_lds (4 per wave)
#pragma unroll
    for (int q = 0; q < 4; ++q) {
      const int idx = wid*4 + q;
      const int pl = idx >> 3, kb = (idx >> 1) & 3, rh = idx & 1;
      const half_t* bp = (pl ? Bl_ : Bh_) + (size_t)(rh*64 + lane)*KD + kc + kb*8;
      gl16(bp, &Bs[(pl*4 + kb)*128 + rh*64]);
    }
    __syncthreads();
    f16x8 aH = asH(As[l4*64 + wid*16 + l15]);
    f16x8 aL = asH(As[(4 + l4)*64 + wid*16 + l15]);
#pragma unroll
    for (int fn = 0; fn < 8; ++fn) {
      f16x8 bH = asH(Bs[l4*128 + fn*16 + l15]);
      f16x8 bL = asH(Bs[(4 + l4)*128 + fn*16 + l15]);
      acc[fn] = MFMA16(aH, bH, acc[fn], 0, 0, 0);
      acc[fn] = MFMA16(aH, bL, acc[fn], 0, 0, 0);
      acc[fn] = MFMA16(aL, bH, acc[fn], 0, 0, 0);
    }
    __syncthreads();
  }

  // epilogue: descale + bias, LN (rows live in 16-lane groups), ReLU, store, z-partials
  float h[8][4], o[8][4];
  float bcol[8], lw[8], lb[8];
#pragma unroll
  for (int fn = 0; fn < 8; ++fn) {
    const int c = fn*16 + l15;
    bcol[fn] = bias[c]; lw[fn] = lnw[c]; lb[fn] = lnb[c];
  }
#pragma unroll
  for (int fn = 0; fn < 8; ++fn)
#pragma unroll
    for (int r = 0; r < 4; ++r) h[fn][r] = acc[fn][r]*(1.f/256.f) + bcol[fn];
#pragma unroll
  for (int r = 0; r < 4; ++r) {
    float s = 0.f, q = 0.f;
#pragma unroll
    for (int fn = 0; fn < 8; ++fn) { s += h[fn][r]; q = fmaf(h[fn][r], h[fn][r], q); }
#pragma unroll
    for (int m = 1; m <= 8; m <<= 1) { s += __shfl_xor(s, m); q += __shfl_xor(q, m); }
    const float mean = s*(1.f/128.f);
    const float var  = q*(1.f/128.f) - mean*mean;
    const float rstd = rsqrtf(var + 1e-5f);
#pragma unroll
    for (int fn = 0; fn < 8; ++fn)
      o[fn][r] = fmaxf(fmaf((h[fn][r] - mean)*rstd, lw[fn], lb[fn]), 0.f);
  }
#pragma unroll
  for (int r = 0; r < 4; ++r) {
    const int grow = row0 + wid*16 + l4*4 + r;
    float* tp = tva + (size_t)grow*384 + colOff;
#pragma unroll
    for (int fn = 0; fn < 8; ++fn) tp[fn*16 + l15] = o[fn][r];
  }
  float gh[6][8];
#pragma unroll
  for (int j = 0; j < 6; ++j)
#pragma unroll
    for (int fn = 0; fn < 8; ++fn) gh[j][fn] = Ghat[j*384 + colOff + fn*16 + l15];
#pragma unroll
  for (int r = 0; r < 4; ++r) {
    const int grow = row0 + wid*16 + l4*4 + r;
    float s6[6];
#pragma unroll
    for (int j = 0; j < 6; ++j) {
      float s = 0.f;
#pragma unroll
      for (int fn = 0; fn < 8; ++fn) s = fmaf(o[fn][r], gh[j][fn], s);
#pragma unroll
      for (int m = 1; m <= 8; m <<= 1) s += __shfl_xor(s, m);
      s6[j] = s;
    }
#pragma unroll
    for (int j = 0; j < 6; ++j)
      if (l15 == j) zpart[(size_t)(srcIdx*PB + grow)*6 + j] = s6[j];
  }
}

// gate combine: z = sum of 3 partials + svec -> softmax -> g
__global__ void k_gate2(const float* __restrict__ zp, const float* __restrict__ svec,
                        float* __restrict__ g)
{
  const int r = blockIdx.x*256 + threadIdx.x;
  float z[6];
#pragma unroll
  for (int j = 0; j < 6; ++j)
    z[j] = zp[(size_t)r*6 + j] + zp[(size_t)(PB + r)*6 + j] + zp[(size_t)(2*PB + r)*6 + j] + svec[j];
  float mx = z[0];
#pragma unroll
  for (int j = 1; j < 6; ++j) mx = fmaxf(mx, z[j]);
  float e[6], s = 0.f;
#pragma unroll
  for (int j = 0; j < 6; ++j) { e[j] = expf(z[j] - mx); s += e[j]; }
  const float inv = 1.f / s;
#pragma unroll
  for (int j = 0; j < 6; ++j) g[(size_t)r*6 + j] = e[j]*inv;
}

// ---------------- f1: gated tva @ N^T (K=800 incl cvec cols), store packed h1 ----------------
__global__ __launch_bounds__(256, 2)
void k_f1(const float* __restrict__ tva, const half_t* __restrict__ Bh_,
          const half_t* __restrict__ Bl_, const float* __restrict__ gbuf,
          const float* __restrict__ bias, unsigned int* __restrict__ h1p)
{
  __shared__ f32x4 As[1024];
  __shared__ f32x4 Bs[1024];
  __shared__ float gS[768];
  const int tid = threadIdx.x;
  const int row0 = blockIdx.x * 128;
  const int colOff = blockIdx.y * 128;
  const int lane = tid & 63, wid = tid >> 6;
  const int wr = wid >> 1, wc = wid & 1;
  const int l15 = lane & 15, l4 = lane >> 4;
  const int sr = tid >> 1, skh = tid & 1;

  for (int i = tid; i < 768; i += 256) gS[i] = gbuf[(size_t)row0*6 + i];
  __syncthreads();

  f32x4 acc[4][4];
#pragma unroll
  for (int i = 0; i < 4; ++i)
#pragma unroll
    for (int j = 0; j < 4; ++j) acc[i][j] = f32x4{0.f, 0.f, 0.f, 0.f};

  for (int kc = 0; kc < 800; kc += 32) {
    float e[16];
    if (kc < 768) {
      const int k0 = kc + skh*16;
      const int br = k0 >> 7;
      const int src = (0x102021 >> (br*4)) & 3;
      const float gsc = gS[sr*6 + br] * 16.f;
      const f32x4* xp = reinterpret_cast<const f32x4*>(tva + (size_t)(row0 + sr)*384 + src*128 + (k0 & 127));
#pragma unroll
      for (int q = 0; q < 4; ++q) {
        f32x4 v = xp[q];
#pragma unroll
        for (int jj = 0; jj < 4; ++jj) e[q*4 + jj] = v[jj]*gsc;
      }
    } else {
#pragma unroll
      for (int j = 0; j < 16; ++j) {
        const int idx = skh*16 + j;
        e[j] = (idx < 6) ? gS[sr*6 + idx]*16.f : 0.f;
      }
    }
#pragma unroll
    for (int q = 0; q < 2; ++q) {
      f16x8 hv, lv;
#pragma unroll
      for (int j = 0; j < 8; ++j) {
        float x = e[q*8 + j];
        half_t h = (half_t)x;
        float lo = x - (float)h;
        hv[j] = h; lv[j] = (half_t)lo;
      }
      As[(skh*2 + q)*128 + sr]       = __builtin_bit_cast(f32x4, hv);
      As[(4 + skh*2 + q)*128 + sr]   = __builtin_bit_cast(f32x4, lv);
    }
#pragma unroll
    for (int q = 0; q < 4; ++q) {
      const int idx = wid*4 + q;
      const int pl = idx >> 3, kb = (idx >> 1) & 3, rh = idx & 1;
      const half_t* bp = (pl ? Bl_ : Bh_) + (size_t)(colOff + rh*64 + lane)*800 + kc + kb*8;
      gl16(bp, &Bs[(pl*4 + kb)*128 + rh*64]);
    }
    __syncthreads();
    f16x8 aH[4], aL[4], bH[4], bL[4];
#pragma unroll
    for (int f = 0; f < 4; ++f) {
      aH[f] = asH(As[l4*128 + wr*64 + f*16 + l15]);
      aL[f] = asH(As[(4 + l4)*128 + wr*64 + f*16 + l15]);
      bH[f] = asH(Bs[l4*128 + wc*64 + f*16 + l15]);
      bL[f] = asH(Bs[(4 + l4)*128 + wc*64 + f*16 + l15]);
    }
#pragma unroll
    for (int fm = 0; fm < 4; ++fm)
#pragma unroll
      for (int fn = 0; fn < 4; ++fn) {
        acc[fm][fn] = MFMA16(aH[fm], bH[fn], acc[fm][fn], 0, 0, 0);
        acc[fm][fn] = MFMA16(aH[fm], bL[fn], acc[fm][fn], 0, 0, 0);
        acc[fm][fn] = MFMA16(aL[fm], bH[fn], acc[fm][fn], 0, 0, 0);
      }
    __syncthreads();
  }

  float bcol[4];
#pragma unroll
  for (int fn = 0; fn < 4; ++fn) bcol[fn] = bias[colOff + wc*64 + fn*16 + l15];
#pragma unroll
  for (int fm = 0; fm < 4; ++fm)
#pragma unroll
    for (int fn = 0; fn < 4; ++fn)
#pragma unroll
      for (int r = 0; r < 4; ++r) {
        float v = acc[fm][fn][r]*(1.f/65536.f) + bcol[fn];
        v = fmaxf(v, 0.f) * 256.f;                       // pre-scale h1 for fp16 split
        half_t hi = (half_t)v;
        float lo = v - (float)hi;
        unsigned u = (unsigned)__builtin_bit_cast(unsigned short, hi)
                   | ((unsigned)__builtin_bit_cast(unsigned short, (half_t)lo) << 16);
        const int grow = row0 + wr*64 + fm*16 + l4*4 + r;
        h1p[(size_t)grow*256 + colOff + wc*64 + fn*16 + l15] = u;
      }
}

// ---------------- f2: h1 @ Wf2^T, fused head partials (h2 never materialized) ----------------
__global__ __launch_bounds__(256, 2)
void k_f2(const unsigned int* __restrict__ h1p, const half_t* __restrict__ Bh_,
          const half_t* __restrict__ Bl_, const float* __restrict__ bias,
          const float* __restrict__ Wout, float* __restrict__ part)
{
  __shared__ f32x4 As[1024];
  __shared__ f32x4 Bs[1024];
  const int tid = threadIdx.x;
  const int row0 = blockIdx.x * 128;
  const int colOff = blockIdx.y * 128;
  const int lane = tid & 63, wid = tid >> 6;
  const int wr = wid >> 1, wc = wid & 1;
  const int l15 = lane & 15, l4 = lane >> 4;
  const int sr = tid >> 1, skh = tid & 1;

  f32x4 acc[4][4];
#pragma unroll
  for (int i = 0; i < 4; ++i)
#pragma unroll
    for (int j = 0; j < 4; ++j) acc[i][j] = f32x4{0.f, 0.f, 0.f, 0.f};

  for (int kc = 0; kc < 256; kc += 32) {
    { // A stage: de-interleave packed h1 (hi|lo<<16) via v_perm
      const u32x4* hp = reinterpret_cast<const u32x4*>(h1p + (size_t)(row0 + sr)*256 + kc + skh*16);
      u32x4 v0 = hp[0], v1 = hp[1], v2 = hp[2], v3 = hp[3];
      u32x4 h0, l0, h1v, l1v;
      h0[0]  = __builtin_amdgcn_perm(v0[1], v0[0], 0x05040100u);
      h0[1]  = __builtin_amdgcn_perm(v0[3], v0[2], 0x05040100u);
      h0[2]  = __builtin_amdgcn_perm(v1[1], v1[0], 0x05040100u);
      h0[3]  = __builtin_amdgcn_perm(v1[3], v1[2], 0x05040100u);
      l0[0]  = __builtin_amdgcn_perm(v0[1], v0[0], 0x07060302u);
      l0[1]  = __builtin_amdgcn_perm(v0[3], v0[2], 0x07060302u);
      l0[2]  = __builtin_amdgcn_perm(v1[1], v1[0], 0x07060302u);
      l0[3]  = __builtin_amdgcn_perm(v1[3], v1[2], 0x07060302u);
      h1v[0] = __builtin_amdgcn_perm(v2[1], v2[0], 0x05040100u);
      h1v[1] = __builtin_amdgcn_perm(v2[3], v2[2], 0x05040100u);
      h1v[2] = __builtin_amdgcn_perm(v3[1], v3[0], 0x05040100u);
      h1v[3] = __builtin_amdgcn_perm(v3[3], v3[2], 0x05040100u);
      l1v[0] = __builtin_amdgcn_perm(v2[1], v2[0], 0x07060302u);
      l1v[1] = __builtin_amdgcn_perm(v2[3], v2[2], 0x07060302u);
      l1v[2] = __builtin_amdgcn_perm(v3[1], v3[0], 0x07060302u);
      l1v[3] = __builtin_amdgcn_perm(v3[3], v3[2], 0x07060302u);
      As[(skh*2 + 0)*128 + sr]     = __builtin_bit_cast(f32x4, h0);
      As[(skh*2 + 1)*128 + sr]     = __builtin_bit_cast(f32x4, h1v);
      As[(4 + skh*2 + 0)*128 + sr] = __builtin_bit_cast(f32x4, l0);
      As[(4 + skh*2 + 1)*128 + sr] = __builtin_bit_cast(f32x4, l1v);
    }
#pragma unroll
    for (int q = 0; q < 4; ++q) {
      const int idx = wid*4 + q;
      const int pl = idx >> 3, kb = (idx >> 1) & 3, rh = idx & 1;
      const half_t* bp = (pl ? Bl_ : Bh_) + (size_t)(colOff + rh*64 + lane)*256 + kc + kb*8;
      gl16(bp, &Bs[(pl*4 + kb)*128 + rh*64]);
    }
    __syncthreads();
    f16x8 aH[4], aL[4], bH[4], bL[4];
#pragma unroll
    for (int f = 0; f < 4; ++f) {
      aH[f] = asH(As[l4*128 + wr*64 + f*16 + l15]);
      aL[f] = asH(As[(4 + l4)*128 + wr*64 + f*16 + l15]);
      bH[f] = asH(Bs[l4*128 + wc*64 + f*16 + l15]);
      bL[f] = asH(Bs[(4 + l4)*128 + wc*64 + f*16 + l15]);
    }
#pragma unroll
    for (int fm = 0; fm < 4; ++fm)
#pragma unroll
      for (int fn = 0; fn < 4; ++fn) {
        acc[fm][fn] = MFMA16(aH[fm], bH[fn], acc[fm][fn], 0, 0, 0);
        acc[fm][fn] = MFMA16(aH[fm], bL[fn], acc[fm][fn], 0, 0, 0);
        acc[fm][fn] = MFMA16(aL[fm], bH[fn], acc[fm][fn], 0, 0, 0);
      }
    __syncthreads();
  }

  // epilogue: relu(h2) then partial dot with Wout rows over this wave's 64 cols
  float bcol[4], w0[4], w1[4];
#pragma unroll
  for (int fn = 0; fn < 4; ++fn) {
    const int c = colOff + wc*64 + fn*16 + l15;
    bcol[fn] = bias[c]; w0[fn] = Wout[c]; w1[fn] = Wout[256 + c];
  }
#pragma unroll
  for (int fm = 0; fm < 4; ++fm)
#pragma unroll
    for (int r = 0; r < 4; ++r) {
      float s0 = 0.f, s1 = 0.f;
#pragma unroll
      for (int fn = 0; fn < 4; ++fn) {
        float hv = fmaxf(acc[fm][fn][r]*(1.f/65536.f) + bcol[fn], 0.f);
        s0 = fmaf(hv, w0[fn], s0);
        s1 = fmaf(hv, w1[fn], s1);
      }
#pragma unroll
      for (int m = 1; m <= 8; m <<= 1) { s0 += __shfl_xor(s0, m); s1 += __shfl_xor(s1, m); }
      if (l15 == fm*4 + r) {
        const int grow = row0 + wr*64 + fm*16 + l4*4 + r;
        float* pp = part + ((size_t)(blockIdx.y*2 + wc)*PB + grow)*2;
        pp[0] = s0; pp[1] = s1;
      }
    }
}

// final combine: out = sum of 4 partial slices + bout
__global__ void k_comb(const float* __restrict__ part, const float* __restrict__ bout,
                       float* __restrict__ out)
{
  const int id = blockIdx.x*256 + threadIdx.x;   // < 65536
  const int j = id & 1;
  float s = bout[j];
#pragma unroll
  for (int s4 = 0; s4 < 4; ++s4) s += part[(size_t)s4*PB*2 + id];
  out[id] = s;
}

} // namespace

extern "C" void kernel_launch(void* const* d_in, const int* in_sizes, int n_in,
                              void* d_out, int out_size, void* d_ws, size_t ws_size,
                              hipStream_t stream)
{
  const float* xt   = (const float*)d_in[0];
  const float* xv   = (const float*)d_in[1];
  const float* xa   = (const float*)d_in[2];
  const float* Wt   = (const float*)d_in[3];
  const float* bt   = (const float*)d_in[4];
  const float* lnwt = (const float*)d_in[5];
  const float* lnbt = (const float*)d_in[6];
  const float* Wv   = (const float*)d_in[7];
  const float* bv   = (const float*)d_in[8];
  const float* lnwv = (const float*)d_in[9];
  const float* lnbv = (const float*)d_in[10];
  const float* Wa   = (const float*)d_in[11];
  const float* ba   = (const float*)d_in[12];
  const float* lnwa = (const float*)d_in[13];
  const float* lnba = (const float*)d_in[14];
  const float* Wqkv = (const float*)d_in[15];
  const float* bqkv = (const float*)d_in[16];
  const float* Wo   = (const float*)d_in[17];
  const float* bo   = (const float*)d_in[18];
  const float* Wg   = (const float*)d_in[19];
  const float* bg   = (const float*)d_in[20];
  const float* Wf1  = (const float*)d_in[21];
  const float* bf1  = (const float*)d_in[22];
  const float* Wf2  = (const float*)d_in[23];
  const float* bf2  = (const float*)d_in[24];
  const float* Woutp= (const float*)d_in[25];
  const float* boutp= (const float*)d_in[26];
  float* out = (float*)d_out;

  float* ws   = (float*)d_ws;
  float* tva  = ws;                              // PB*384
  float* g    = tva  + (size_t)PB*384;           // PB*6
  float* h1pf = g    + (size_t)PB*6;             // PB*256 u32 (aliases zpart)
  float* M    = h1pf + (size_t)PB*256;           // 6*128*128
  float* beff = M    + 6*128*128;                // 768
  float* p    = beff + 768;
  half_t* Nh  = (half_t*)p;   p += 256*800/2;    // 256*800 halfs
  half_t* Nl  = (half_t*)p;   p += 256*800/2;
  half_t* Wth = (half_t*)p;   p += 128*768/2;
  half_t* Wtl = (half_t*)p;   p += 128*768/2;
  half_t* Wvh = (half_t*)p;   p += 128*512/2;
  half_t* Wvl = (half_t*)p;   p += 128*512/2;
  half_t* Wah = (half_t*)p;   p += 128*384/2;
  half_t* Wal = (half_t*)p;   p += 128*384/2;
  half_t* Wf2h= (half_t*)p;   p += 256*256/2;
  half_t* Wf2l= (half_t*)p;   p += 256*256/2;
  float* Ghat = p;            p += 6*384;
  float* svec = p;            p += 8;
  unsigned int* h1p = (unsigned int*)h1pf;
  float* zpart = h1pf;                           // 3*PB*6, dead before f1 writes h1p
  float* part  = tva;                            // 4*PB*2, tva dead before f2

  // weight composition + splits
  k_weff<<<768, 128, 0, stream>>>(Wqkv, bqkv, Wo, bo, M, beff);
  k_nbig2<<<1536, 128, 0, stream>>>(Wf1, M, beff, Nh, Nl);
  k_ghat<<<18, 128, 0, stream>>>(M, Wg, Ghat);
  k_svec<<<6, 128, 0, stream>>>(beff, Wg, bg, svec);
  k_split<<<(128*768 + 255)/256, 256, 0, stream>>>(Wt, Wth, Wtl, 256.f, 128*768);
  k_split<<<(128*512 + 255)/256, 256, 0, stream>>>(Wv, Wvh, Wvl, 256.f, 128*512);
  k_split<<<(128*384 + 255)/256, 256, 0, stream>>>(Wa, Wah, Wal, 256.f, 128*384);
  k_split<<<(256*256 + 255)/256, 256, 0, stream>>>(Wf2, Wf2h, Wf2l, 256.f, 256*256);

  // projections (fused LN+ReLU+gate-partials)
  k_proj<768><<<512, 256, 0, stream>>>(xt, Wth, Wtl, bt, lnwt, lnbt, Ghat, tva, zpart, 0, 0);
  k_proj<512><<<512, 256, 0, stream>>>(xv, Wvh, Wvl, bv, lnwv, lnbv, Ghat, tva, zpart, 128, 1);
  k_proj<384><<<512, 256, 0, stream>>>(xa, Wah, Wal, ba, lnwa, lnba, Ghat, tva, zpart, 256, 2);

  // gate
  k_gate2<<<PB/256, 256, 0, stream>>>(zpart, svec, g);

  // f1 (gated fused branch+f1, cvec folded into K=800), f2 (fused head partials), combine
  k_f1<<<dim3(256, 2), 256, 0, stream>>>(tva, Nh, Nl, g, bf1, h1p);
  k_f2<<<dim3(256, 2), 256, 0, stream>>>(h1p, Wf2h, Wf2l, bf2, Woutp, part);
  k_comb<<<256, 256, 0, stream>>>(part, boutp, out);
}